// Round 2
// baseline (188.442 us; speedup 1.0000x reference)
//
#include <hip/hip_runtime.h>

// QuantizedBn2d (per-cluster quantized batchnorm requant), bit==8.
// Shapes: x[B=32, C=256, H=56, W=56] (int-valued fp32), params per cluster K=8.
//
// IMPORTANT semantics note: the reference runs under JAX with x64 DISABLED,
// so every .astype(jnp.int64) is silently int32. The gemmlowp high-mul
// (x * M0) WRAPS in int32, and ((prod + nudge) >> 31) on int32 is always
// 0 or -1. We replicate exact int32-wraparound semantics using unsigned
// arithmetic (signed overflow is UB in C++).
//
// Memory-bound elementwise: ~205 MB traffic -> roofline ~33us @ 6.3 TB/s.

#define BB 32
#define CC 256
#define HWN 3136               // 56*56
#define NTOT (BB * CC * HWN)   // 25,690,112
#define N4 (NTOT / 4)          // 6,422,528 float4s

__device__ __forceinline__ float qbn_elem(float xf, int m, int w, int b,
                                          int pre, int post, int m0,
                                          int z3v) {
    int sub = ((int)xf - m) * w + b;            // int32 subsum (no overflow)
    int x32 = sub << pre;                       // left-shift branch (neg shift); fits int32
    // gemmlowp high mul with int32 WRAPAROUND (matches jax x64-off semantics)
    int prod = (int)((unsigned)x32 * (unsigned)m0);
    int nudge = (prod >= 0) ? (1 << 30) : (1 - (1 << 30));
    int mul = ((int)((unsigned)prod + (unsigned)nudge)) >> 31;   // in {0,-1}
    // rounding right shift by post (identity when post==0), int32 domain
    int mask = (1 << post) - 1;
    int rem = mul & mask;
    int thr = (mask >> 1) + (mul < 0);
    int tot = (mul >> post) + (rem > thr);
    tot += z3v;
    tot = tot < -128 ? -128 : (tot > 127 ? 127 : tot);   // 8-bit clamp
    return (float)tot;
}

__global__ __launch_bounds__(256) void qbn_kernel(
    const float* __restrict__ x,
    const int* __restrict__ bc,
    const int* __restrict__ z3,
    const int* __restrict__ M0,
    const int* __restrict__ shift,
    const int* __restrict__ mean,
    const int* __restrict__ wds,
    const int* __restrict__ bias,
    float* __restrict__ out)
{
    int idx4 = blockIdx.x * 256 + threadIdx.x;
    if (idx4 >= N4) return;
    int base = idx4 << 2;                 // element index, fits int32
    int plane = base / HWN;               // (b*C + c); all 4 elems same plane (HWN%4==0)
    int b = plane >> 8;                   // C == 256
    int c = plane & 255;

    int k = bc[b];                        // cluster id (wave-uniform per batch)
    int m  = mean[k * CC + c];
    int w  = wds [k * CC + c];
    int bi = bias[k * CC + c];
    int s  = shift[k];
    int pre  = s < 0 ? -s : 0;
    int post = s > 0 ?  s : 0;
    int m0 = M0[k];
    int z3v = z3[k];

    float4 xv = *(const float4*)(x + base);
    float4 ov;
    ov.x = qbn_elem(xv.x, m, w, bi, pre, post, m0, z3v);
    ov.y = qbn_elem(xv.y, m, w, bi, pre, post, m0, z3v);
    ov.z = qbn_elem(xv.z, m, w, bi, pre, post, m0, z3v);
    ov.w = qbn_elem(xv.w, m, w, bi, pre, post, m0, z3v);
    *(float4*)(out + base) = ov;
}

extern "C" void kernel_launch(void* const* d_in, const int* in_sizes, int n_in,
                              void* d_out, int out_size, void* d_ws, size_t ws_size,
                              hipStream_t stream) {
    const float* x   = (const float*)d_in[0];
    const int* bc    = (const int*)d_in[1];
    const int* z3    = (const int*)d_in[2];
    const int* M0    = (const int*)d_in[3];
    const int* shift = (const int*)d_in[4];
    const int* mean  = (const int*)d_in[5];
    const int* wds   = (const int*)d_in[6];
    const int* bias  = (const int*)d_in[7];
    float* out = (float*)d_out;

    dim3 grid(N4 / 256);   // 25088 blocks, exact cover
    dim3 block(256);
    qbn_kernel<<<grid, block, 0, stream>>>(x, bc, z3, M0, shift, mean, wds, bias, out);
}

// Round 4
// 185.991 us; speedup vs baseline: 1.0132x; 1.0132x over previous
//
#include <hip/hip_runtime.h>

// QuantizedBn2d (per-cluster quantized batchnorm requant), bit==8.
// Shapes: x[B=32, C=256, H=56, W=56] (int-valued fp32), params per cluster K=8.
//
// Semantics note: the reference runs under JAX with x64 DISABLED, so every
// .astype(jnp.int64) is int32 and the gemmlowp high-mul WRAPS in int32.
// Under wrap, mul = (prod+nudge)>>31 is always in {0,-1}; the rounding
// right-shift by post then collapses to:
//     r = (post < 2) ? mul : 0     (verified case-by-case for mul in {0,-1})
// and with z3 in [-64,63], tot = z3 + r is in [-65,63] -> 8-bit clamp is a
// provable no-op. We keep exact int32-wrap semantics via unsigned arithmetic.
//
// Memory-bound elementwise: ~205 MB traffic -> kernel floor ~30us @ 6.8 TB/s.

#define BB 32
#define CC 256
#define HWN 3136               // 56*56
#define NTOT (BB * CC * HWN)   // 25,690,112
#define N4 (NTOT / 4)          // 6,422,528 float4s

typedef float f32x4 __attribute__((ext_vector_type(4)));  // true vector type:
// __builtin_nontemporal_* requires int/float/pointer or vector thereof
// (HIP_vector_type<float,4> is a struct and is rejected).

__device__ __forceinline__ float qbn_elem(float xf, int m, int w, int b,
                                          int pre, int m0, int sel, int z3v) {
    int sub = ((int)xf - m) * w + b;                     // int32 subsum (no overflow)
    unsigned x32 = ((unsigned)sub) << pre;               // left-shift branch (neg shift)
    unsigned prod = x32 * (unsigned)m0;                  // int32 wraparound mul
    // nudge = prod>=0 ? 2^30 : 1-2^30 ; add with wrap
    int ps = ((int)prod) >> 31;                          // 0 or -1
    unsigned nudge = 0x40000000u + ((unsigned)ps & 0x80000001u);
    int mul = ((int)(prod + nudge)) >> 31;               // in {0,-1}
    int tot = z3v + (mul & sel);                         // sel = (post<2) ? -1 : 0
    return (float)tot;                                   // clamp provably no-op
}

__global__ __launch_bounds__(256) void qbn_kernel(
    const float* __restrict__ x,
    const int* __restrict__ bc,
    const int* __restrict__ z3,
    const int* __restrict__ M0,
    const int* __restrict__ shift,
    const int* __restrict__ mean,
    const int* __restrict__ wds,
    const int* __restrict__ bias,
    float* __restrict__ out)
{
    int idx4 = blockIdx.x * 256 + threadIdx.x;
    if (idx4 >= N4) return;
    int base = idx4 << 2;                 // element index, fits int32
    int plane = base / HWN;               // (b*C + c); all 4 elems same plane (HWN%4==0)
    int b = plane >> 8;                   // C == 256
    int c = plane & 255;

    int k = bc[b];                        // cluster id (wave-uniform per batch)
    int m  = mean[k * CC + c];
    int w  = wds [k * CC + c];
    int bi = bias[k * CC + c];
    int s  = shift[k];
    int pre  = s < 0 ? -s : 0;
    int post = s > 0 ?  s : 0;
    int sel  = (post < 2) ? -1 : 0;       // rounding-rshift collapse (see header)
    int m0 = M0[k];
    int z3v = z3[k];

    f32x4 xv = __builtin_nontemporal_load((const f32x4*)(x + base));
    f32x4 ov;
    ov.x = qbn_elem(xv.x, m, w, bi, pre, m0, sel, z3v);
    ov.y = qbn_elem(xv.y, m, w, bi, pre, m0, sel, z3v);
    ov.z = qbn_elem(xv.z, m, w, bi, pre, m0, sel, z3v);
    ov.w = qbn_elem(xv.w, m, w, bi, pre, m0, sel, z3v);
    __builtin_nontemporal_store(ov, (f32x4*)(out + base));
}

extern "C" void kernel_launch(void* const* d_in, const int* in_sizes, int n_in,
                              void* d_out, int out_size, void* d_ws, size_t ws_size,
                              hipStream_t stream) {
    const float* x   = (const float*)d_in[0];
    const int* bc    = (const int*)d_in[1];
    const int* z3    = (const int*)d_in[2];
    const int* M0    = (const int*)d_in[3];
    const int* shift = (const int*)d_in[4];
    const int* mean  = (const int*)d_in[5];
    const int* wds   = (const int*)d_in[6];
    const int* bias  = (const int*)d_in[7];
    float* out = (float*)d_out;

    dim3 grid(N4 / 256);   // 25088 blocks, exact cover
    dim3 block(256);
    qbn_kernel<<<grid, block, 0, stream>>>(x, bc, z3, M0, shift, mean, wds, bias, out);
}